// Round 10
// baseline (249.425 us; speedup 1.0000x reference)
//
#include <hip/hip_runtime.h>
#include <math.h>

#define SHIFT 8              // coarse bucket = dst >> 8  (256 nodes per bucket)
#define NBMAX 1024           // max coarse buckets (N/256 = 586 for N=150000)
#define CAP   4096           // fixed bucket capacity (mean 3413, sd 58 -> +11 sigma)
#define TILE  4096           // edges per partition block (489 blocks, 36KB LDS -> 4/CU)
#define HSCALE 64.0f         // fp8 storage scale

typedef float v2f __attribute__((ext_vector_type(2)));
typedef short bf16x8 __attribute__((ext_vector_type(8)));
typedef float f32x4 __attribute__((ext_vector_type(4)));

__device__ __forceinline__ unsigned short f2bf(float f) {
    unsigned u = __float_as_uint(f);
    unsigned r = u + 0x7FFFu + ((u >> 16) & 1u);   // RNE
    return (unsigned short)(r >> 16);
}
__device__ __forceinline__ unsigned pack2bf(float lo, float hi) {
    return (unsigned)f2bf(lo) | ((unsigned)f2bf(hi) << 16);
}
__device__ __forceinline__ float bflo(unsigned u) { return __uint_as_float(u << 16); }
__device__ __forceinline__ float bfhi(unsigned u) { return __uint_as_float(u & 0xFFFF0000u); }

// ---------------- sort kernels ----------------

// LDS-staged bucket partition (wave-shfl scan, 4 blocks/CU):
//  A: LDS histogram; B: 1024-bin scan via per-wave shfl_up (2 barriers, was 20)
//     + one global atomic per nonempty bin; C: scatter tile into LDS
//  (bucket-ordered); D: linear sweep emitting contiguous global runs.
//  gcur holds COUNTS (memset 0 by host). Blocks 0..7 transpose W1/W2.
__global__ __launch_bounds__(512) void k_partition(
    const int* __restrict__ src, const int* __restrict__ dst, int E,
    unsigned* __restrict__ gcur, unsigned* __restrict__ pairs, int NB,
    const float* __restrict__ W1, const float* __restrict__ W2,
    unsigned short* __restrict__ WT1, unsigned short* __restrict__ WT2) {
    __shared__ unsigned lh[NBMAX];       // counts -> placement cursor
    __shared__ unsigned lbase[NBMAX];    // exclusive local scan
    __shared__ unsigned gbase[NBMAX];    // global run base
    __shared__ unsigned wsum[8];         // per-wave scan totals
    __shared__ unsigned spair[TILE];     // staged pairs, bucket-ordered
    __shared__ unsigned short sb[TILE];  // bucket tag per staged entry
    int t = threadIdx.x;
    {
        int gt = blockIdx.x * 512 + t;
        if (gt < 4096) {
            int n = gt & 63, k = gt >> 6;
            WT1[n * 64 + k] = f2bf(W1[k * 64 + n]);
            WT2[n * 64 + k] = f2bf(W2[k * 64 + n]);
        }
    }
    lh[t] = 0; lh[t + 512] = 0;
    __syncthreads();
    int base = blockIdx.x * TILE;
    int end = min(E, base + TILE);
    for (int i = base + t; i < end; i += 512)
        atomicAdd(&lh[((unsigned)dst[i]) >> SHIFT], 1u);
    __syncthreads();
    // ---- 1024-bin exclusive scan: 2 bins/thread, per-wave shfl_up scan ----
    unsigned c0 = lh[2 * t], c1 = lh[2 * t + 1];
    unsigned s = c0 + c1;
    unsigned val = s;
    int lane = t & 63;
#pragma unroll
    for (int off = 1; off < 64; off <<= 1) {
        unsigned x = __shfl_up(val, off, 64);
        if (lane >= off) val += x;
    }
    if (lane == 63) wsum[t >> 6] = val;
    __syncthreads();
    {
        unsigned pre = 0;
        int w8 = t >> 6;
#pragma unroll
        for (int i = 0; i < 8; ++i) if (i < w8) pre += wsum[i];
        unsigned e0 = pre + val - s;          // exclusive before bin 2t
        unsigned e1 = e0 + c0;
        if (c0) gbase[2*t]   = (unsigned)(2*t) * CAP + atomicAdd(&gcur[2*t], c0);
        if (c1) gbase[2*t+1] = (unsigned)(2*t+1) * CAP + atomicAdd(&gcur[2*t+1], c1);
        lbase[2*t] = e0; lbase[2*t+1] = e1;   // exclusive scan (phase D)
        lh[2*t] = e0;    lh[2*t+1] = e1;      // placement cursor (phase C)
    }
    __syncthreads();
    for (int i = base + t; i < end; i += 512) {
        unsigned d = (unsigned)dst[i];
        unsigned b = d >> SHIFT;
        unsigned p = atomicAdd(&lh[b], 1u);
        spair[p] = ((d & 255u) << 18) | (unsigned)src[i];
        sb[p] = (unsigned short)b;
    }
    __syncthreads();
    int cnt = end - base;
    for (int i = t; i < cnt; i += 512) {
        unsigned b = sb[i];
        pairs[gbase[b] + ((unsigned)i - lbase[b])] = spair[i];
    }
}

// merged: blocks [0,NB) = per-bucket counting sort (wave-shfl scan);
// blocks [NB,..) = linear1 (HT=4, BIN=0) at 512 threads.
__global__ __launch_bounds__(512) void k_buck_lin(
    const unsigned* __restrict__ pairs, const unsigned* __restrict__ gcur,
    unsigned* __restrict__ beg, unsigned* __restrict__ endd,
    int* __restrict__ srt, int N, int NB,
    const float* __restrict__ xa, const float* __restrict__ xb, int split,
    const unsigned short* __restrict__ WTg,
    const float* __restrict__ a_src, const float* __restrict__ a_dst,
    unsigned char* __restrict__ h, float* __restrict__ as_out,
    float* __restrict__ ad_out) {
    __shared__ union U {
        struct { unsigned lh[256]; unsigned lcur[256]; unsigned sh[8]; int ssrt[CAP]; } b;
        struct { unsigned short sX[64 * 72]; unsigned short sWT[64 * 72]; float sH[64 * 68]; } l;
    } u;
    int t = threadIdx.x;

    if ((int)blockIdx.x < NB) {
        // ---------------- bucket counting sort ----------------
        int b = blockIdx.x;
        unsigned s0 = (unsigned)b * CAP;
        int cnt = (int)gcur[b];                 // counts
        if (t < 256) u.b.lh[t] = 0;
        __syncthreads();
        for (int i = t; i < cnt; i += 512)
            atomicAdd(&u.b.lh[pairs[s0 + i] >> 18], 1u);
        __syncthreads();
        // 256-bin exclusive scan via per-wave shfl_up (2 barriers, was 16)
        unsigned deg_t = 0, val = 0;
        if (t < 256) {
            deg_t = u.b.lh[t];
            val = deg_t;
            int lane = t & 63;
#pragma unroll
            for (int off = 1; off < 64; off <<= 1) {
                unsigned x = __shfl_up(val, off, 64);
                if (lane >= off) val += x;
            }
            if (lane == 63) u.b.sh[t >> 6] = val;
        }
        __syncthreads();
        if (t < 256) {
            int w = t >> 6;
            unsigned pre = 0;
#pragma unroll
            for (int i = 0; i < 4; ++i) if (i < w) pre += u.b.sh[i];
            unsigned excl = pre + val - deg_t;
            u.b.lcur[t] = excl;
            int node = (b << SHIFT) + t;
            if (node < N) { beg[node] = s0 + excl; endd[node] = s0 + excl + deg_t; }
        }
        __syncthreads();
        for (int i = t; i < cnt; i += 512) {
            unsigned pk = pairs[s0 + i];
            unsigned p = atomicAdd(&u.b.lcur[pk >> 18], 1u);
            u.b.ssrt[p] = (int)(pk & 0x3FFFFu);
        }
        __syncthreads();
        for (int i = t; i < cnt; i += 512) srt[s0 + i] = u.b.ssrt[i];
    } else {
        // ---------------- linear1 (HT=4, BIN=0), 512 threads ----------------
        int nodeBase = ((int)blockIdx.x - NB) * 64;
        {
            int r = t >> 3, c8 = (t & 7) * 8;       // 8 bf16 columns per thread
            int n = nodeBase + r;
            float4 v0 = {0,0,0,0}, v1 = {0,0,0,0};
            if (n < N) {
                const float* row = (n < split) ? (xa + (size_t)n * 64 + c8)
                                               : (xb + (size_t)(n - split) * 64 + c8);
                const float4* r4 = (const float4*)row;
                v0 = r4[0]; v1 = r4[1];
            }
            uint4 A = make_uint4(pack2bf(v0.x, v0.y), pack2bf(v0.z, v0.w),
                                 pack2bf(v1.x, v1.y), pack2bf(v1.z, v1.w));
            *(uint4*)(void*)(u.l.sX + r * 72 + c8) = A;
            const uint4* wsrc = (const uint4*)(const void*)WTg;
            *(uint4*)(void*)(u.l.sWT + r * 72 + c8) = wsrc[r * 8 + (c8 >> 3)];
        }
        __syncthreads();
        {
            int lane = t & 63, w = t >> 6;
            if (w < 4) {
                int gl = lane & 15, quad = lane >> 4;
                int m0 = w * 16;
                const bf16x8 a0 = *(const bf16x8*)(void*)(u.l.sX + (m0 + gl) * 72 + quad * 8);
                const bf16x8 a1 = *(const bf16x8*)(void*)(u.l.sX + (m0 + gl) * 72 + 32 + quad * 8);
                f32x4 acc[4];
#pragma unroll
                for (int tt = 0; tt < 4; ++tt) {
                    const bf16x8 b0 = *(const bf16x8*)(void*)(u.l.sWT + (tt * 16 + gl) * 72 + quad * 8);
                    const bf16x8 b1 = *(const bf16x8*)(void*)(u.l.sWT + (tt * 16 + gl) * 72 + 32 + quad * 8);
                    f32x4 c = {0.f, 0.f, 0.f, 0.f};
                    c = __builtin_amdgcn_mfma_f32_16x16x32_bf16(a0, b0, c, 0, 0, 0);
                    c = __builtin_amdgcn_mfma_f32_16x16x32_bf16(a1, b1, c, 0, 0, 0);
                    acc[tt] = c;
                }
#pragma unroll
                for (int tt = 0; tt < 4; ++tt)
#pragma unroll
                    for (int rr = 0; rr < 4; ++rr)
                        u.l.sH[(m0 + quad * 4 + rr) * 68 + tt * 16 + gl] = acc[tt][rr];
            }
        }
        __syncthreads();
        if (t < 256) {
            int m = t >> 2, p = t & 3;
            int n = nodeBase + m;
            const float4* sp = (const float4*)(void*)(u.l.sH + m * 68 + p * 16);
            float4 q0 = sp[0], q1 = sp[1], q2 = sp[2], q3 = sp[3];
            float hv[16] = {q0.x,q0.y,q0.z,q0.w, q1.x,q1.y,q1.z,q1.w,
                            q2.x,q2.y,q2.z,q2.w, q3.x,q3.y,q3.z,q3.w};
            if (n < N) {
                unsigned dwords[4];
#pragma unroll
                for (int q = 0; q < 4; ++q) {
                    int d0 = __builtin_amdgcn_cvt_pk_fp8_f32(hv[4*q] * HSCALE, hv[4*q+1] * HSCALE, 0, false);
                    d0 = __builtin_amdgcn_cvt_pk_fp8_f32(hv[4*q+2] * HSCALE, hv[4*q+3] * HSCALE, d0, true);
                    dwords[q] = (unsigned)d0;
                }
                ((uint4*)h)[(size_t)n * 4 + p] = make_uint4(dwords[0], dwords[1], dwords[2], dwords[3]);
                float ps = 0.f, pd = 0.f;
#pragma unroll
                for (int i = 0; i < 16; ++i) {
                    ps = fmaf(hv[i], a_src[p * 16 + i], ps);
                    pd = fmaf(hv[i], a_dst[p * 16 + i], pd);
                }
                as_out[n * 4 + p] = ps;
                ad_out[n * 4 + p] = pd;
            }
        }
    }
}

// ---------------- GAT kernels ----------------

// MFMA linear (256 threads) — used for layer 2 only (HT=1, BIN=1).
template <int HT, int BIN>
__global__ __launch_bounds__(256) void k_linear_mfma(
    const void* __restrict__ xav, const void* __restrict__ xbv, int split,
    const unsigned short* __restrict__ WTg,
    const float* __restrict__ a_src, const float* __restrict__ a_dst,
    unsigned char* __restrict__ h, float* __restrict__ as_out,
    float* __restrict__ ad_out, int N) {
    __shared__ unsigned short sX[64 * 72];
    __shared__ unsigned short sWT[64 * 72];
    __shared__ float sH[64 * 68];
    int t = threadIdx.x;
    int nodeBase = blockIdx.x * 64;

    {
        int r = t >> 2, c4 = (t & 3) * 16;
        int n = nodeBase + r;
        uint4 A = {0,0,0,0}, Bv = {0,0,0,0};
        if (BIN) {
            if (n < N) {
                const unsigned short* row = (const unsigned short*)xav + (size_t)n * 64 + c4;
                A  = ((const uint4*)(const void*)row)[0];
                Bv = ((const uint4*)(const void*)row)[1];
            }
        } else {
            float4 v0 = {0,0,0,0}, v1 = {0,0,0,0}, v2 = {0,0,0,0}, v3 = {0,0,0,0};
            if (n < N) {
                const float* row = (n < split) ? ((const float*)xav + (size_t)n * 64 + c4)
                                               : ((const float*)xbv + (size_t)(n - split) * 64 + c4);
                const float4* r4 = (const float4*)row;
                v0 = r4[0]; v1 = r4[1]; v2 = r4[2]; v3 = r4[3];
            }
            A  = make_uint4(pack2bf(v0.x, v0.y), pack2bf(v0.z, v0.w),
                            pack2bf(v1.x, v1.y), pack2bf(v1.z, v1.w));
            Bv = make_uint4(pack2bf(v2.x, v2.y), pack2bf(v2.z, v2.w),
                            pack2bf(v3.x, v3.y), pack2bf(v3.z, v3.w));
        }
        *(uint4*)(void*)(sX + r * 72 + c4) = A;
        *(uint4*)(void*)(sX + r * 72 + c4 + 8) = Bv;
        const uint4* wsrc = (const uint4*)(const void*)WTg;
        int base = (r * 64 + c4) >> 3;
        *(uint4*)(void*)(sWT + r * 72 + c4) = wsrc[base];
        *(uint4*)(void*)(sWT + r * 72 + c4 + 8) = wsrc[base + 1];
    }
    __syncthreads();

    {
        int lane = t & 63, w = t >> 6;
        int gl = lane & 15, quad = lane >> 4;
        int m0 = w * 16;
        const bf16x8 a0 = *(const bf16x8*)(void*)(sX + (m0 + gl) * 72 + quad * 8);
        const bf16x8 a1 = *(const bf16x8*)(void*)(sX + (m0 + gl) * 72 + 32 + quad * 8);
        f32x4 acc[4];
#pragma unroll
        for (int tt = 0; tt < 4; ++tt) {
            const bf16x8 b0 = *(const bf16x8*)(void*)(sWT + (tt * 16 + gl) * 72 + quad * 8);
            const bf16x8 b1 = *(const bf16x8*)(void*)(sWT + (tt * 16 + gl) * 72 + 32 + quad * 8);
            f32x4 c = {0.f, 0.f, 0.f, 0.f};
            c = __builtin_amdgcn_mfma_f32_16x16x32_bf16(a0, b0, c, 0, 0, 0);
            c = __builtin_amdgcn_mfma_f32_16x16x32_bf16(a1, b1, c, 0, 0, 0);
            acc[tt] = c;
        }
#pragma unroll
        for (int tt = 0; tt < 4; ++tt)
#pragma unroll
            for (int rr = 0; rr < 4; ++rr)
                sH[(m0 + quad * 4 + rr) * 68 + tt * 16 + gl] = acc[tt][rr];
    }
    __syncthreads();

    {
        int m = t >> 2, p = t & 3;
        int n = nodeBase + m;
        const float4* sp = (const float4*)(void*)(sH + m * 68 + p * 16);
        float4 q0 = sp[0], q1 = sp[1], q2 = sp[2], q3 = sp[3];
        float hv[16] = {q0.x,q0.y,q0.z,q0.w, q1.x,q1.y,q1.z,q1.w,
                        q2.x,q2.y,q2.z,q2.w, q3.x,q3.y,q3.z,q3.w};
        if (n < N) {
            unsigned dwords[4];
#pragma unroll
            for (int q = 0; q < 4; ++q) {
                int d0 = __builtin_amdgcn_cvt_pk_fp8_f32(hv[4*q] * HSCALE, hv[4*q+1] * HSCALE, 0, false);
                d0 = __builtin_amdgcn_cvt_pk_fp8_f32(hv[4*q+2] * HSCALE, hv[4*q+3] * HSCALE, d0, true);
                dwords[q] = (unsigned)d0;
            }
            ((uint4*)h)[(size_t)n * 4 + p] = make_uint4(dwords[0], dwords[1], dwords[2], dwords[3]);
            float ps = 0.f, pd = 0.f;
#pragma unroll
            for (int i = 0; i < 16; ++i) {
                ps = fmaf(hv[i], a_src[p * 16 + i], ps);
                pd = fmaf(hv[i], a_dst[p * 16 + i], pd);
            }
            if (HT == 4) {
                as_out[n * 4 + p] = ps;
                ad_out[n * 4 + p] = pd;
            } else {
                ps += __shfl_xor(ps, 1, 64); ps += __shfl_xor(ps, 2, 64);
                pd += __shfl_xor(pd, 1, 64); pd += __shfl_xor(pd, 2, 64);
                if (p == 0) { as_out[n] = ps; ad_out[n] = pd; }
            }
        }
    }
}

// fused GAT aggregation — R5 body (at the random-64B-gather roofline:
// ~176 MB fabric traffic @ ~3.55 TB/s; do not touch).
template <int HT>
__global__ __launch_bounds__(256, 4) void k_gat(
                      const int* __restrict__ srt, const unsigned* __restrict__ beg,
                      const unsigned* __restrict__ endd,
                      const unsigned* __restrict__ hq, const float* __restrict__ as,
                      const float* __restrict__ ad, const float* __restrict__ b,
                      unsigned* __restrict__ xout, int N) {
    __shared__ unsigned s_vo[4][4][40];                  // [wave][group][slot(32)+pad8]
    __shared__ float    s_w[4][4][(HT == 4) ? 164 : 40]; // HT=4: hh*40+slot, +4 pad

    int t = threadIdx.x;
    int lane = t & 63;
    int wv = t >> 6;
    int gl = lane & 15;
    int g  = lane >> 4;
    int wid = (int)((blockIdx.x * blockDim.x + t) >> 6);
    int d = wid * 4 + g;
    bool active = d < N;
    const int hh = (HT == 4) ? (gl >> 2) : 0;
    const unsigned gl4 = (unsigned)gl << 2;
    const char* hqb = (const char*)hq;
    const char* asb = (const char*)as;

    float adv = 0.f, l = 0.f;
    float a0 = 0.f, a1 = 0.f, a2 = 0.f, a3 = 0.f;
    int kb = 0, end = 0;
    if (active) {
        adv = ad[d * HT + hh];
        float e0 = as[d * HT + hh] + adv;      // self-loop term
        e0 = (e0 > 0.f) ? e0 : 0.2f * e0;
        float w0 = __expf(e0);
        unsigned dw = hq[(size_t)d * 16 + gl];
        v2f lo = __builtin_amdgcn_cvt_pk_f32_fp8((int)dw, false);
        v2f hi = __builtin_amdgcn_cvt_pk_f32_fp8((int)dw, true);
        l = w0;
        a0 = w0 * lo.x; a1 = w0 * lo.y; a2 = w0 * hi.x; a3 = w0 * hi.y;
        kb = (int)beg[d];
        end = (int)endd[d];
    }

    int m = end - kb;                          // group-uniform (0 for inactive)
    while (__ballot(m > 0)) {
        unsigned v0 = 0, v1 = 0;
        if (gl < m)      v0 = ((unsigned)srt[kb + gl]) << 6;       // h-row byte offset
        if (gl + 16 < m) v1 = ((unsigned)srt[kb + gl + 16]) << 6;

        if (HT == 1) {
            // as-gathers FIRST (oldest in vmcnt queue -> exp won't wait on rows)
            float as0 = 0.f, as1 = 0.f;
            if (gl < m)      as0 = *(const float*)(asb + (v0 >> 4));   // as[s] : s*4
            if (gl + 16 < m) as1 = *(const float*)(asb + (v1 >> 4));
            s_vo[wv][g][gl]      = v0;
            s_vo[wv][g][gl + 16] = v1;
            asm volatile("s_waitcnt lgkmcnt(0)" ::: "memory");
            __builtin_amdgcn_sched_barrier(0);
            // broadcast-read all 32 offsets, issue 32 row gathers
            unsigned rr[32];
            const uint4* vob = (const uint4*)(const void*)&s_vo[wv][g][0];
#pragma unroll
            for (int c = 0; c < 8; ++c) {
                uint4 vv = vob[c];
                rr[4*c+0] = *(const unsigned*)(hqb + (vv.x + gl4));
                rr[4*c+1] = *(const unsigned*)(hqb + (vv.y + gl4));
                rr[4*c+2] = *(const unsigned*)(hqb + (vv.z + gl4));
                rr[4*c+3] = *(const unsigned*)(hqb + (vv.w + gl4));
            }
            // weights (overlap in-flight row gathers)
            float w0 = 0.f, w1 = 0.f;
            if (gl < m) {
                float e = as0 + adv;
                e = (e > 0.f) ? e : 0.2f * e;
                w0 = __expf(e);
            }
            if (gl + 16 < m) {
                float e = as1 + adv;
                e = (e > 0.f) ? e : 0.2f * e;
                w1 = __expf(e);
            }
            // hoisted denominator: one reduce instead of 32 serial adds
            float wsum = w0 + w1;
            wsum += __shfl_xor(wsum, 1, 64);
            wsum += __shfl_xor(wsum, 2, 64);
            wsum += __shfl_xor(wsum, 4, 64);
            wsum += __shfl_xor(wsum, 8, 64);
            l += wsum;
            s_w[wv][g][gl]      = w0;
            s_w[wv][g][gl + 16] = w1;
            asm volatile("s_waitcnt lgkmcnt(0)" ::: "memory");
            __builtin_amdgcn_sched_barrier(0);
            // accumulate slots 0..31
            const float4* wrd = (const float4*)(const void*)&s_w[wv][g][0];
#pragma unroll
            for (int c = 0; c < 8; ++c) {
                float4 wc = wrd[c];
                float wj[4] = {wc.x, wc.y, wc.z, wc.w};
#pragma unroll
                for (int j = 0; j < 4; ++j) {
                    float w = wj[j];
                    unsigned rv = rr[4*c + j];
                    v2f lo = __builtin_amdgcn_cvt_pk_f32_fp8((int)rv, false);
                    v2f hi = __builtin_amdgcn_cvt_pk_f32_fp8((int)rv, true);
                    a0 = fmaf(w, lo.x, a0);
                    a1 = fmaf(w, lo.y, a1);
                    a2 = fmaf(w, hi.x, a2);
                    a3 = fmaf(w, hi.y, a3);
                }
            }
        } else {
            // HT == 4
            s_vo[wv][g][gl]      = v0;
            s_vo[wv][g][gl + 16] = v1;
            asm volatile("s_waitcnt lgkmcnt(0)" ::: "memory");
            __builtin_amdgcn_sched_barrier(0);
            // per-lane weight slots: head hh = gl>>2, edges (gl&3)*8 .. +7
            int eb = (gl & 3) << 3;
            const uint4* vop = (const uint4*)(const void*)&s_vo[wv][g][eb];
            uint4 va = vop[0], vb = vop[1];
            unsigned vs[8] = {va.x, va.y, va.z, va.w, vb.x, vb.y, vb.z, vb.w};
            // as-gathers FIRST (oldest in vmcnt queue)
            float av[8];
#pragma unroll
            for (int r = 0; r < 8; ++r)
                av[r] = *(const float*)(asb + ((vs[r] >> 2) + ((unsigned)hh << 2)));
            // broadcast-read all 32 offsets, issue 32 row gathers
            unsigned rr[32];
            const uint4* vob = (const uint4*)(const void*)&s_vo[wv][g][0];
#pragma unroll
            for (int c = 0; c < 8; ++c) {
                uint4 vv = vob[c];
                rr[4*c+0] = *(const unsigned*)(hqb + (vv.x + gl4));
                rr[4*c+1] = *(const unsigned*)(hqb + (vv.y + gl4));
                rr[4*c+2] = *(const unsigned*)(hqb + (vv.z + gl4));
                rr[4*c+3] = *(const unsigned*)(hqb + (vv.w + gl4));
            }
            // weights (overlap in-flight row gathers)
            float wq[8];
#pragma unroll
            for (int r = 0; r < 8; ++r) {
                wq[r] = 0.f;
                if (eb + r < m) {
                    float e = av[r] + adv;
                    e = (e > 0.f) ? e : 0.2f * e;
                    wq[r] = __expf(e);
                }
            }
            // hoisted per-head denominator: reduce over the 4 lanes of head hh
            float wsum = ((wq[0] + wq[1]) + (wq[2] + wq[3]))
                       + ((wq[4] + wq[5]) + (wq[6] + wq[7]));
            wsum += __shfl_xor(wsum, 1, 64);
            wsum += __shfl_xor(wsum, 2, 64);
            l += wsum;
            float4* wp = (float4*)(void*)&s_w[wv][g][hh * 40 + eb];
            wp[0] = make_float4(wq[0], wq[1], wq[2], wq[3]);
            wp[1] = make_float4(wq[4], wq[5], wq[6], wq[7]);
            asm volatile("s_waitcnt lgkmcnt(0)" ::: "memory");
            __builtin_amdgcn_sched_barrier(0);
            // accumulate slots 0..31
            const float4* wrd = (const float4*)(const void*)&s_w[wv][g][hh * 40];
#pragma unroll
            for (int c = 0; c < 8; ++c) {
                float4 wc = wrd[c];
                float wj[4] = {wc.x, wc.y, wc.z, wc.w};
#pragma unroll
                for (int j = 0; j < 4; ++j) {
                    float w = wj[j];
                    unsigned rv = rr[4*c + j];
                    v2f lo = __builtin_amdgcn_cvt_pk_f32_fp8((int)rv, false);
                    v2f hi = __builtin_amdgcn_cvt_pk_f32_fp8((int)rv, true);
                    a0 = fmaf(w, lo.x, a0);
                    a1 = fmaf(w, lo.y, a1);
                    a2 = fmaf(w, hi.x, a2);
                    a3 = fmaf(w, hi.y, a3);
                }
            }
        }
        kb += 32;
        m = end - kb;
    }

    if (active) {
        float4 bb4 = ((const float4*)b)[gl];
        float rs = 1.f / (l * HSCALE);
        float v0 = a0 * rs + bb4.x;
        float v1 = a1 * rs + bb4.y;
        float v2 = a2 * rs + bb4.z;
        float v3 = a3 * rs + bb4.w;
        float o0 = (v0 > 0.f) ? v0 : expm1f(v0);
        float o1 = (v1 > 0.f) ? v1 : expm1f(v1);
        float o2 = (v2 > 0.f) ? v2 : expm1f(v2);
        float o3 = (v3 > 0.f) ? v3 : expm1f(v3);
        ((uint2*)xout)[(size_t)d * 16 + gl] = make_uint2(pack2bf(o0, o1), pack2bf(o2, o3));
    }
}

// out[i] = sigmoid(dot(x[u], x[v])) — bf16 x rows, 4 pairs per wave, 16 lanes each
__global__ void k_dot_sig(const uint2* __restrict__ x2, const int* __restrict__ uidx,
                          const int* __restrict__ vidx, float* __restrict__ out,
                          int batch, int numUsers) {
    int lane = threadIdx.x & 63;
    int gl = lane & 15;
    int q = (int)(((blockIdx.x * blockDim.x + threadIdx.x) >> 6) * 4 + (lane >> 4));
    if (q >= batch) return;
    int u = uidx[q];
    int v = vidx[q] + numUsers;
    uint2 a = x2[(size_t)u * 16 + gl];
    uint2 c = x2[(size_t)v * 16 + gl];
    float p = bflo(a.x) * bflo(c.x) + bfhi(a.x) * bfhi(c.x)
            + bflo(a.y) * bflo(c.y) + bfhi(a.y) * bfhi(c.y);
#pragma unroll
    for (int off = 1; off < 16; off <<= 1) p += __shfl_xor(p, off, 64);
    if (gl == 0) out[q] = 1.f / (1.f + __expf(-p));
}

// ---------------- host launch ----------------

static inline int cdiv(long long a, long long b) { return (int)((a + b - 1) / b); }

extern "C" void kernel_launch(void* const* d_in, const int* in_sizes, int n_in,
                              void* d_out, int out_size, void* d_ws, size_t ws_size,
                              hipStream_t stream) {
    const int* edge_index = (const int*)d_in[0];
    const int* buidx      = (const int*)d_in[1];
    const int* biidx      = (const int*)d_in[2];
    const float* user_emb = (const float*)d_in[3];
    const float* item_emb = (const float*)d_in[4];
    const float* W1     = (const float*)d_in[5];
    const float* a_src1 = (const float*)d_in[6];
    const float* a_dst1 = (const float*)d_in[7];
    const float* b1     = (const float*)d_in[8];
    const float* W2     = (const float*)d_in[9];
    const float* a_src2 = (const float*)d_in[10];
    const float* a_dst2 = (const float*)d_in[11];
    const float* b2     = (const float*)d_in[12];
    float* out = (float*)d_out;

    const int E  = in_sizes[0] / 2;
    const int B  = in_sizes[1];
    const int NU = in_sizes[3] / 64;
    const int NI = in_sizes[4] / 64;
    const int N  = NU + NI;
    const int NB = cdiv(N, 1 << SHIFT);     // 586 for N=150000 (<= NBMAX)

    const int* src = edge_index;
    const int* dst = edge_index + E;

    // workspace carve (4-byte units)
    float* ws = (float*)d_ws;
    size_t off = 0;
    unsigned* x_buf  = (unsigned*)(ws + off); off += (size_t)N * 32;   // bf16 x (128B rows)
    unsigned* h_buf  = (unsigned*)(ws + off); off += (size_t)N * 16;   // fp8 h (64B rows)
    float*    as_b   = ws + off; off += (size_t)N * 4;
    float*    ad_b   = ws + off; off += (size_t)N * 4;
    unsigned* gcur_b = (unsigned*)(ws + off); off += NBMAX;
    unsigned* beg_b  = (unsigned*)(ws + off); off += (size_t)N;
    unsigned* end_b  = (unsigned*)(ws + off); off += (size_t)N;
    unsigned* pairs_b= (unsigned*)(ws + off); off += (size_t)NB * CAP;
    int*      srt_b  = (int*)(ws + off); off += (size_t)NB * CAP;
    unsigned short* wt1_b = (unsigned short*)(ws + off); off += 2048;
    unsigned short* wt2_b = (unsigned short*)(ws + off); off += 2048;

    const int BS = 256;

    // ---------- prep (folded) + LDS-staged bucket partition ----------
    hipMemsetAsync(gcur_b, 0, NBMAX * sizeof(unsigned), stream);
    k_partition<<<cdiv(E, TILE), 512, 0, stream>>>(src, dst, E, gcur_b, pairs_b, NB,
                                                   W1, W2, wt1_b, wt2_b);

    // ---------- bucket sort || layer-1 linear (merged, independent) ----------
    k_buck_lin<<<NB + cdiv(N, 64), 512, 0, stream>>>(
        pairs_b, gcur_b, beg_b, end_b, srt_b, N, NB,
        user_emb, item_emb, NU, wt1_b, a_src1, a_dst1,
        (unsigned char*)h_buf, as_b, ad_b);

    // ---------- gat layer 1 (H=4) ----------
    k_gat<4><<<cdiv((long long)N * 16, BS), BS, 0, stream>>>(
        srt_b, beg_b, end_b, h_buf, as_b, ad_b, b1, x_buf, N);

    // ---------- layer 2 : H=1, F=64 (bf16 x) ----------
    k_linear_mfma<1, 1><<<cdiv(N, 64), BS, 0, stream>>>(x_buf, x_buf, N, wt2_b,
                                                        a_src2, a_dst2,
                                                        (unsigned char*)h_buf, as_b, ad_b, N);
    k_gat<1><<<cdiv((long long)N * 16, BS), BS, 0, stream>>>(
        srt_b, beg_b, end_b, h_buf, as_b, ad_b, b2, x_buf, N);

    // ---------- final: sigmoid(dot) ----------
    k_dot_sig<<<cdiv((long long)B * 16, BS), BS, 0, stream>>>(
        (const uint2*)x_buf, buidx, biidx, out, B, NU);
}

// Round 11
// 241.192 us; speedup vs baseline: 1.0341x; 1.0341x over previous
//
#include <hip/hip_runtime.h>
#include <math.h>

#define SHIFT 8              // coarse bucket = dst >> 8  (256 nodes per bucket)
#define NBMAX 1024           // max coarse buckets (N/256 = 586 for N=150000)
#define CAP   4096           // fixed bucket capacity (mean 3413, sd 58 -> +11 sigma)
#define TILE  8192           // edges per partition block (245 blocks; long phase-D runs)
#define HSCALE 64.0f         // fp8 storage scale

typedef float v2f __attribute__((ext_vector_type(2)));
typedef short bf16x8 __attribute__((ext_vector_type(8)));
typedef float f32x4 __attribute__((ext_vector_type(4)));

__device__ __forceinline__ unsigned short f2bf(float f) {
    unsigned u = __float_as_uint(f);
    unsigned r = u + 0x7FFFu + ((u >> 16) & 1u);   // RNE
    return (unsigned short)(r >> 16);
}
__device__ __forceinline__ unsigned pack2bf(float lo, float hi) {
    return (unsigned)f2bf(lo) | ((unsigned)f2bf(hi) << 16);
}
__device__ __forceinline__ float bflo(unsigned u) { return __uint_as_float(u << 16); }
__device__ __forceinline__ float bfhi(unsigned u) { return __uint_as_float(u & 0xFFFF0000u); }

// ---------------- sort kernels ----------------

// LDS-staged bucket partition (R9 configuration — best measured):
//  phase A: LDS histogram; B: 1024-bin scan + one global atomic per nonempty
//  bin (reserve run); C: scatter tile into LDS (bucket-ordered); D: linear
//  sweep emitting contiguous global runs (~14 edges = 56B) instead of 4B
//  scatter. gcur holds COUNTS (memset 0 by host); base q*CAP folded here.
//  Blocks 0..7 also transpose W1/W2 -> bf16 WT (prep_w folded in).
//  NOTE: TILE=4096 (2x blocks) measured WORSE (-9us): halves run length,
//  doubles per-bin atomics. Keep 8192.
__global__ __launch_bounds__(512) void k_partition(
    const int* __restrict__ src, const int* __restrict__ dst, int E,
    unsigned* __restrict__ gcur, unsigned* __restrict__ pairs, int NB,
    const float* __restrict__ W1, const float* __restrict__ W2,
    unsigned short* __restrict__ WT1, unsigned short* __restrict__ WT2) {
    __shared__ unsigned lh[NBMAX];       // counts -> placement cursor
    __shared__ unsigned lbase[NBMAX];    // exclusive local scan
    __shared__ unsigned gbase[NBMAX];    // global run base
    __shared__ unsigned spair[TILE];     // staged pairs, bucket-ordered
    __shared__ unsigned short sb[TILE];  // bucket tag per staged entry
    int t = threadIdx.x;
    {
        int gt = blockIdx.x * 512 + t;
        if (gt < 4096) {
            int n = gt & 63, k = gt >> 6;
            WT1[n * 64 + k] = f2bf(W1[k * 64 + n]);
            WT2[n * 64 + k] = f2bf(W2[k * 64 + n]);
        }
    }
    lh[t] = 0; lh[t + 512] = 0;
    __syncthreads();
    int base = blockIdx.x * TILE;
    int end = min(E, base + TILE);
    for (int i = base + t; i < end; i += 512)
        atomicAdd(&lh[((unsigned)dst[i]) >> SHIFT], 1u);
    __syncthreads();
    // inclusive scan of 1024 bins, 2 bins/thread (Hillis-Steele)
    lbase[t] = lh[t]; lbase[t + 512] = lh[t + 512];
    __syncthreads();
    for (int off = 1; off < 1024; off <<= 1) {
        unsigned a0 = (t >= off) ? lbase[t - off] : 0u;
        unsigned a1 = ((t + 512) >= off) ? lbase[t + 512 - off] : 0u;
        __syncthreads();
        lbase[t] += a0;
        lbase[t + 512] += a1;
        __syncthreads();
    }
    {
        unsigned c0 = lh[t], c1 = lh[t + 512];
        unsigned e0 = lbase[t] - c0, e1 = lbase[t + 512] - c1;
        if (c0) gbase[t] = (unsigned)t * CAP + atomicAdd(&gcur[t], c0);
        if (c1) gbase[t + 512] = (unsigned)(t + 512) * CAP + atomicAdd(&gcur[t + 512], c1);
        __syncthreads();
        lbase[t] = e0; lbase[t + 512] = e1;   // exclusive scan (phase D)
        lh[t] = e0; lh[t + 512] = e1;         // placement cursor (phase C)
    }
    __syncthreads();
    for (int i = base + t; i < end; i += 512) {
        unsigned d = (unsigned)dst[i];
        unsigned b = d >> SHIFT;
        unsigned p = atomicAdd(&lh[b], 1u);
        spair[p] = ((d & 255u) << 18) | (unsigned)src[i];
        sb[p] = (unsigned short)b;
    }
    __syncthreads();
    int cnt = end - base;
    for (int i = t; i < cnt; i += 512) {
        unsigned b = sb[i];
        pairs[gbase[b] + ((unsigned)i - lbase[b])] = spair[i];
    }
}

// merged: blocks [0,NB) = per-bucket counting sort; blocks [NB,..) = linear1
// (HT=4, BIN=0) at 512 threads. The two halves are independent; one dispatch
// overlaps them and removes a kernel boundary.
__global__ __launch_bounds__(512) void k_buck_lin(
    const unsigned* __restrict__ pairs, const unsigned* __restrict__ gcur,
    unsigned* __restrict__ beg, unsigned* __restrict__ endd,
    int* __restrict__ srt, int N, int NB,
    const float* __restrict__ xa, const float* __restrict__ xb, int split,
    const unsigned short* __restrict__ WTg,
    const float* __restrict__ a_src, const float* __restrict__ a_dst,
    unsigned char* __restrict__ h, float* __restrict__ as_out,
    float* __restrict__ ad_out) {
    __shared__ union U {
        struct { unsigned lh[256]; unsigned lcur[256]; unsigned sh[256]; int ssrt[CAP]; } b;
        struct { unsigned short sX[64 * 72]; unsigned short sWT[64 * 72]; float sH[64 * 68]; } l;
    } u;
    int t = threadIdx.x;

    if ((int)blockIdx.x < NB) {
        // ---------------- bucket counting sort ----------------
        int b = blockIdx.x;
        unsigned s0 = (unsigned)b * CAP;
        int cnt = (int)gcur[b];                 // counts
        if (t < 256) u.b.lh[t] = 0;
        __syncthreads();
        for (int i = t; i < cnt; i += 512)
            atomicAdd(&u.b.lh[pairs[s0 + i] >> 18], 1u);
        __syncthreads();
        unsigned deg_t = 0;
        if (t < 256) { deg_t = u.b.lh[t]; u.b.sh[t] = deg_t; }
        __syncthreads();
        for (int off = 1; off < 256; off <<= 1) {
            unsigned x = 0;
            if (t < 256 && t >= off) x = u.b.sh[t - off];
            __syncthreads();
            if (t < 256) u.b.sh[t] += x;
            __syncthreads();
        }
        if (t < 256) {
            unsigned excl = u.b.sh[t] - deg_t;
            u.b.lcur[t] = excl;
            int node = (b << SHIFT) + t;
            if (node < N) { beg[node] = s0 + excl; endd[node] = s0 + excl + deg_t; }
        }
        __syncthreads();
        for (int i = t; i < cnt; i += 512) {
            unsigned pk = pairs[s0 + i];
            unsigned p = atomicAdd(&u.b.lcur[pk >> 18], 1u);
            u.b.ssrt[p] = (int)(pk & 0x3FFFFu);
        }
        __syncthreads();
        for (int i = t; i < cnt; i += 512) srt[s0 + i] = u.b.ssrt[i];
    } else {
        // ---------------- linear1 (HT=4, BIN=0), 512 threads ----------------
        int nodeBase = ((int)blockIdx.x - NB) * 64;
        {
            int r = t >> 3, c8 = (t & 7) * 8;       // 8 bf16 columns per thread
            int n = nodeBase + r;
            float4 v0 = {0,0,0,0}, v1 = {0,0,0,0};
            if (n < N) {
                const float* row = (n < split) ? (xa + (size_t)n * 64 + c8)
                                               : (xb + (size_t)(n - split) * 64 + c8);
                const float4* r4 = (const float4*)row;
                v0 = r4[0]; v1 = r4[1];
            }
            uint4 A = make_uint4(pack2bf(v0.x, v0.y), pack2bf(v0.z, v0.w),
                                 pack2bf(v1.x, v1.y), pack2bf(v1.z, v1.w));
            *(uint4*)(void*)(u.l.sX + r * 72 + c8) = A;
            const uint4* wsrc = (const uint4*)(const void*)WTg;
            *(uint4*)(void*)(u.l.sWT + r * 72 + c8) = wsrc[r * 8 + (c8 >> 3)];
        }
        __syncthreads();
        {
            int lane = t & 63, w = t >> 6;
            if (w < 4) {
                int gl = lane & 15, quad = lane >> 4;
                int m0 = w * 16;
                const bf16x8 a0 = *(const bf16x8*)(void*)(u.l.sX + (m0 + gl) * 72 + quad * 8);
                const bf16x8 a1 = *(const bf16x8*)(void*)(u.l.sX + (m0 + gl) * 72 + 32 + quad * 8);
                f32x4 acc[4];
#pragma unroll
                for (int tt = 0; tt < 4; ++tt) {
                    const bf16x8 b0 = *(const bf16x8*)(void*)(u.l.sWT + (tt * 16 + gl) * 72 + quad * 8);
                    const bf16x8 b1 = *(const bf16x8*)(void*)(u.l.sWT + (tt * 16 + gl) * 72 + 32 + quad * 8);
                    f32x4 c = {0.f, 0.f, 0.f, 0.f};
                    c = __builtin_amdgcn_mfma_f32_16x16x32_bf16(a0, b0, c, 0, 0, 0);
                    c = __builtin_amdgcn_mfma_f32_16x16x32_bf16(a1, b1, c, 0, 0, 0);
                    acc[tt] = c;
                }
#pragma unroll
                for (int tt = 0; tt < 4; ++tt)
#pragma unroll
                    for (int rr = 0; rr < 4; ++rr)
                        u.l.sH[(m0 + quad * 4 + rr) * 68 + tt * 16 + gl] = acc[tt][rr];
            }
        }
        __syncthreads();
        if (t < 256) {
            int m = t >> 2, p = t & 3;
            int n = nodeBase + m;
            const float4* sp = (const float4*)(void*)(u.l.sH + m * 68 + p * 16);
            float4 q0 = sp[0], q1 = sp[1], q2 = sp[2], q3 = sp[3];
            float hv[16] = {q0.x,q0.y,q0.z,q0.w, q1.x,q1.y,q1.z,q1.w,
                            q2.x,q2.y,q2.z,q2.w, q3.x,q3.y,q3.z,q3.w};
            if (n < N) {
                unsigned dwords[4];
#pragma unroll
                for (int q = 0; q < 4; ++q) {
                    int d0 = __builtin_amdgcn_cvt_pk_fp8_f32(hv[4*q] * HSCALE, hv[4*q+1] * HSCALE, 0, false);
                    d0 = __builtin_amdgcn_cvt_pk_fp8_f32(hv[4*q+2] * HSCALE, hv[4*q+3] * HSCALE, d0, true);
                    dwords[q] = (unsigned)d0;
                }
                ((uint4*)h)[(size_t)n * 4 + p] = make_uint4(dwords[0], dwords[1], dwords[2], dwords[3]);
                float ps = 0.f, pd = 0.f;
#pragma unroll
                for (int i = 0; i < 16; ++i) {
                    ps = fmaf(hv[i], a_src[p * 16 + i], ps);
                    pd = fmaf(hv[i], a_dst[p * 16 + i], pd);
                }
                as_out[n * 4 + p] = ps;
                ad_out[n * 4 + p] = pd;
            }
        }
    }
}

// ---------------- GAT kernels ----------------

// MFMA linear (256 threads) — used for layer 2 only (HT=1, BIN=1).
template <int HT, int BIN>
__global__ __launch_bounds__(256) void k_linear_mfma(
    const void* __restrict__ xav, const void* __restrict__ xbv, int split,
    const unsigned short* __restrict__ WTg,
    const float* __restrict__ a_src, const float* __restrict__ a_dst,
    unsigned char* __restrict__ h, float* __restrict__ as_out,
    float* __restrict__ ad_out, int N) {
    __shared__ unsigned short sX[64 * 72];
    __shared__ unsigned short sWT[64 * 72];
    __shared__ float sH[64 * 68];
    int t = threadIdx.x;
    int nodeBase = blockIdx.x * 64;

    {
        int r = t >> 2, c4 = (t & 3) * 16;
        int n = nodeBase + r;
        uint4 A = {0,0,0,0}, Bv = {0,0,0,0};
        if (BIN) {
            if (n < N) {
                const unsigned short* row = (const unsigned short*)xav + (size_t)n * 64 + c4;
                A  = ((const uint4*)(const void*)row)[0];
                Bv = ((const uint4*)(const void*)row)[1];
            }
        } else {
            float4 v0 = {0,0,0,0}, v1 = {0,0,0,0}, v2 = {0,0,0,0}, v3 = {0,0,0,0};
            if (n < N) {
                const float* row = (n < split) ? ((const float*)xav + (size_t)n * 64 + c4)
                                               : ((const float*)xbv + (size_t)(n - split) * 64 + c4);
                const float4* r4 = (const float4*)row;
                v0 = r4[0]; v1 = r4[1]; v2 = r4[2]; v3 = r4[3];
            }
            A  = make_uint4(pack2bf(v0.x, v0.y), pack2bf(v0.z, v0.w),
                            pack2bf(v1.x, v1.y), pack2bf(v1.z, v1.w));
            Bv = make_uint4(pack2bf(v2.x, v2.y), pack2bf(v2.z, v2.w),
                            pack2bf(v3.x, v3.y), pack2bf(v3.z, v3.w));
        }
        *(uint4*)(void*)(sX + r * 72 + c4) = A;
        *(uint4*)(void*)(sX + r * 72 + c4 + 8) = Bv;
        const uint4* wsrc = (const uint4*)(const void*)WTg;
        int base = (r * 64 + c4) >> 3;
        *(uint4*)(void*)(sWT + r * 72 + c4) = wsrc[base];
        *(uint4*)(void*)(sWT + r * 72 + c4 + 8) = wsrc[base + 1];
    }
    __syncthreads();

    {
        int lane = t & 63, w = t >> 6;
        int gl = lane & 15, quad = lane >> 4;
        int m0 = w * 16;
        const bf16x8 a0 = *(const bf16x8*)(void*)(sX + (m0 + gl) * 72 + quad * 8);
        const bf16x8 a1 = *(const bf16x8*)(void*)(sX + (m0 + gl) * 72 + 32 + quad * 8);
        f32x4 acc[4];
#pragma unroll
        for (int tt = 0; tt < 4; ++tt) {
            const bf16x8 b0 = *(const bf16x8*)(void*)(sWT + (tt * 16 + gl) * 72 + quad * 8);
            const bf16x8 b1 = *(const bf16x8*)(void*)(sWT + (tt * 16 + gl) * 72 + 32 + quad * 8);
            f32x4 c = {0.f, 0.f, 0.f, 0.f};
            c = __builtin_amdgcn_mfma_f32_16x16x32_bf16(a0, b0, c, 0, 0, 0);
            c = __builtin_amdgcn_mfma_f32_16x16x32_bf16(a1, b1, c, 0, 0, 0);
            acc[tt] = c;
        }
#pragma unroll
        for (int tt = 0; tt < 4; ++tt)
#pragma unroll
            for (int rr = 0; rr < 4; ++rr)
                sH[(m0 + quad * 4 + rr) * 68 + tt * 16 + gl] = acc[tt][rr];
    }
    __syncthreads();

    {
        int m = t >> 2, p = t & 3;
        int n = nodeBase + m;
        const float4* sp = (const float4*)(void*)(sH + m * 68 + p * 16);
        float4 q0 = sp[0], q1 = sp[1], q2 = sp[2], q3 = sp[3];
        float hv[16] = {q0.x,q0.y,q0.z,q0.w, q1.x,q1.y,q1.z,q1.w,
                        q2.x,q2.y,q2.z,q2.w, q3.x,q3.y,q3.z,q3.w};
        if (n < N) {
            unsigned dwords[4];
#pragma unroll
            for (int q = 0; q < 4; ++q) {
                int d0 = __builtin_amdgcn_cvt_pk_fp8_f32(hv[4*q] * HSCALE, hv[4*q+1] * HSCALE, 0, false);
                d0 = __builtin_amdgcn_cvt_pk_fp8_f32(hv[4*q+2] * HSCALE, hv[4*q+3] * HSCALE, d0, true);
                dwords[q] = (unsigned)d0;
            }
            ((uint4*)h)[(size_t)n * 4 + p] = make_uint4(dwords[0], dwords[1], dwords[2], dwords[3]);
            float ps = 0.f, pd = 0.f;
#pragma unroll
            for (int i = 0; i < 16; ++i) {
                ps = fmaf(hv[i], a_src[p * 16 + i], ps);
                pd = fmaf(hv[i], a_dst[p * 16 + i], pd);
            }
            if (HT == 4) {
                as_out[n * 4 + p] = ps;
                ad_out[n * 4 + p] = pd;
            } else {
                ps += __shfl_xor(ps, 1, 64); ps += __shfl_xor(ps, 2, 64);
                pd += __shfl_xor(pd, 1, 64); pd += __shfl_xor(pd, 2, 64);
                if (p == 0) { as_out[n] = ps; ad_out[n] = pd; }
            }
        }
    }
}

// fused GAT aggregation — R5 body (at the random-64B-gather roofline:
// ~176 MB fabric traffic @ ~3.55 TB/s; do not touch).
template <int HT>
__global__ __launch_bounds__(256, 4) void k_gat(
                      const int* __restrict__ srt, const unsigned* __restrict__ beg,
                      const unsigned* __restrict__ endd,
                      const unsigned* __restrict__ hq, const float* __restrict__ as,
                      const float* __restrict__ ad, const float* __restrict__ b,
                      unsigned* __restrict__ xout, int N) {
    __shared__ unsigned s_vo[4][4][40];                  // [wave][group][slot(32)+pad8]
    __shared__ float    s_w[4][4][(HT == 4) ? 164 : 40]; // HT=4: hh*40+slot, +4 pad

    int t = threadIdx.x;
    int lane = t & 63;
    int wv = t >> 6;
    int gl = lane & 15;
    int g  = lane >> 4;
    int wid = (int)((blockIdx.x * blockDim.x + t) >> 6);
    int d = wid * 4 + g;
    bool active = d < N;
    const int hh = (HT == 4) ? (gl >> 2) : 0;
    const unsigned gl4 = (unsigned)gl << 2;
    const char* hqb = (const char*)hq;
    const char* asb = (const char*)as;

    float adv = 0.f, l = 0.f;
    float a0 = 0.f, a1 = 0.f, a2 = 0.f, a3 = 0.f;
    int kb = 0, end = 0;
    if (active) {
        adv = ad[d * HT + hh];
        float e0 = as[d * HT + hh] + adv;      // self-loop term
        e0 = (e0 > 0.f) ? e0 : 0.2f * e0;
        float w0 = __expf(e0);
        unsigned dw = hq[(size_t)d * 16 + gl];
        v2f lo = __builtin_amdgcn_cvt_pk_f32_fp8((int)dw, false);
        v2f hi = __builtin_amdgcn_cvt_pk_f32_fp8((int)dw, true);
        l = w0;
        a0 = w0 * lo.x; a1 = w0 * lo.y; a2 = w0 * hi.x; a3 = w0 * hi.y;
        kb = (int)beg[d];
        end = (int)endd[d];
    }

    int m = end - kb;                          // group-uniform (0 for inactive)
    while (__ballot(m > 0)) {
        unsigned v0 = 0, v1 = 0;
        if (gl < m)      v0 = ((unsigned)srt[kb + gl]) << 6;       // h-row byte offset
        if (gl + 16 < m) v1 = ((unsigned)srt[kb + gl + 16]) << 6;

        if (HT == 1) {
            // as-gathers FIRST (oldest in vmcnt queue -> exp won't wait on rows)
            float as0 = 0.f, as1 = 0.f;
            if (gl < m)      as0 = *(const float*)(asb + (v0 >> 4));   // as[s] : s*4
            if (gl + 16 < m) as1 = *(const float*)(asb + (v1 >> 4));
            s_vo[wv][g][gl]      = v0;
            s_vo[wv][g][gl + 16] = v1;
            asm volatile("s_waitcnt lgkmcnt(0)" ::: "memory");
            __builtin_amdgcn_sched_barrier(0);
            // broadcast-read all 32 offsets, issue 32 row gathers
            unsigned rr[32];
            const uint4* vob = (const uint4*)(const void*)&s_vo[wv][g][0];
#pragma unroll
            for (int c = 0; c < 8; ++c) {
                uint4 vv = vob[c];
                rr[4*c+0] = *(const unsigned*)(hqb + (vv.x + gl4));
                rr[4*c+1] = *(const unsigned*)(hqb + (vv.y + gl4));
                rr[4*c+2] = *(const unsigned*)(hqb + (vv.z + gl4));
                rr[4*c+3] = *(const unsigned*)(hqb + (vv.w + gl4));
            }
            // weights (overlap in-flight row gathers)
            float w0 = 0.f, w1 = 0.f;
            if (gl < m) {
                float e = as0 + adv;
                e = (e > 0.f) ? e : 0.2f * e;
                w0 = __expf(e);
            }
            if (gl + 16 < m) {
                float e = as1 + adv;
                e = (e > 0.f) ? e : 0.2f * e;
                w1 = __expf(e);
            }
            // hoisted denominator: one reduce instead of 32 serial adds
            float wsum = w0 + w1;
            wsum += __shfl_xor(wsum, 1, 64);
            wsum += __shfl_xor(wsum, 2, 64);
            wsum += __shfl_xor(wsum, 4, 64);
            wsum += __shfl_xor(wsum, 8, 64);
            l += wsum;
            s_w[wv][g][gl]      = w0;
            s_w[wv][g][gl + 16] = w1;
            asm volatile("s_waitcnt lgkmcnt(0)" ::: "memory");
            __builtin_amdgcn_sched_barrier(0);
            // accumulate slots 0..31
            const float4* wrd = (const float4*)(const void*)&s_w[wv][g][0];
#pragma unroll
            for (int c = 0; c < 8; ++c) {
                float4 wc = wrd[c];
                float wj[4] = {wc.x, wc.y, wc.z, wc.w};
#pragma unroll
                for (int j = 0; j < 4; ++j) {
                    float w = wj[j];
                    unsigned rv = rr[4*c + j];
                    v2f lo = __builtin_amdgcn_cvt_pk_f32_fp8((int)rv, false);
                    v2f hi = __builtin_amdgcn_cvt_pk_f32_fp8((int)rv, true);
                    a0 = fmaf(w, lo.x, a0);
                    a1 = fmaf(w, lo.y, a1);
                    a2 = fmaf(w, hi.x, a2);
                    a3 = fmaf(w, hi.y, a3);
                }
            }
        } else {
            // HT == 4
            s_vo[wv][g][gl]      = v0;
            s_vo[wv][g][gl + 16] = v1;
            asm volatile("s_waitcnt lgkmcnt(0)" ::: "memory");
            __builtin_amdgcn_sched_barrier(0);
            // per-lane weight slots: head hh = gl>>2, edges (gl&3)*8 .. +7
            int eb = (gl & 3) << 3;
            const uint4* vop = (const uint4*)(const void*)&s_vo[wv][g][eb];
            uint4 va = vop[0], vb = vop[1];
            unsigned vs[8] = {va.x, va.y, va.z, va.w, vb.x, vb.y, vb.z, vb.w};
            // as-gathers FIRST (oldest in vmcnt queue)
            float av[8];
#pragma unroll
            for (int r = 0; r < 8; ++r)
                av[r] = *(const float*)(asb + ((vs[r] >> 2) + ((unsigned)hh << 2)));
            // broadcast-read all 32 offsets, issue 32 row gathers
            unsigned rr[32];
            const uint4* vob = (const uint4*)(const void*)&s_vo[wv][g][0];
#pragma unroll
            for (int c = 0; c < 8; ++c) {
                uint4 vv = vob[c];
                rr[4*c+0] = *(const unsigned*)(hqb + (vv.x + gl4));
                rr[4*c+1] = *(const unsigned*)(hqb + (vv.y + gl4));
                rr[4*c+2] = *(const unsigned*)(hqb + (vv.z + gl4));
                rr[4*c+3] = *(const unsigned*)(hqb + (vv.w + gl4));
            }
            // weights (overlap in-flight row gathers)
            float wq[8];
#pragma unroll
            for (int r = 0; r < 8; ++r) {
                wq[r] = 0.f;
                if (eb + r < m) {
                    float e = av[r] + adv;
                    e = (e > 0.f) ? e : 0.2f * e;
                    wq[r] = __expf(e);
                }
            }
            // hoisted per-head denominator: reduce over the 4 lanes of head hh
            float wsum = ((wq[0] + wq[1]) + (wq[2] + wq[3]))
                       + ((wq[4] + wq[5]) + (wq[6] + wq[7]));
            wsum += __shfl_xor(wsum, 1, 64);
            wsum += __shfl_xor(wsum, 2, 64);
            l += wsum;
            float4* wp = (float4*)(void*)&s_w[wv][g][hh * 40 + eb];
            wp[0] = make_float4(wq[0], wq[1], wq[2], wq[3]);
            wp[1] = make_float4(wq[4], wq[5], wq[6], wq[7]);
            asm volatile("s_waitcnt lgkmcnt(0)" ::: "memory");
            __builtin_amdgcn_sched_barrier(0);
            // accumulate slots 0..31
            const float4* wrd = (const float4*)(const void*)&s_w[wv][g][hh * 40];
#pragma unroll
            for (int c = 0; c < 8; ++c) {
                float4 wc = wrd[c];
                float wj[4] = {wc.x, wc.y, wc.z, wc.w};
#pragma unroll
                for (int j = 0; j < 4; ++j) {
                    float w = wj[j];
                    unsigned rv = rr[4*c + j];
                    v2f lo = __builtin_amdgcn_cvt_pk_f32_fp8((int)rv, false);
                    v2f hi = __builtin_amdgcn_cvt_pk_f32_fp8((int)rv, true);
                    a0 = fmaf(w, lo.x, a0);
                    a1 = fmaf(w, lo.y, a1);
                    a2 = fmaf(w, hi.x, a2);
                    a3 = fmaf(w, hi.y, a3);
                }
            }
        }
        kb += 32;
        m = end - kb;
    }

    if (active) {
        float4 bb4 = ((const float4*)b)[gl];
        float rs = 1.f / (l * HSCALE);
        float v0 = a0 * rs + bb4.x;
        float v1 = a1 * rs + bb4.y;
        float v2 = a2 * rs + bb4.z;
        float v3 = a3 * rs + bb4.w;
        float o0 = (v0 > 0.f) ? v0 : expm1f(v0);
        float o1 = (v1 > 0.f) ? v1 : expm1f(v1);
        float o2 = (v2 > 0.f) ? v2 : expm1f(v2);
        float o3 = (v3 > 0.f) ? v3 : expm1f(v3);
        ((uint2*)xout)[(size_t)d * 16 + gl] = make_uint2(pack2bf(o0, o1), pack2bf(o2, o3));
    }
}

// out[i] = sigmoid(dot(x[u], x[v])) — bf16 x rows, 4 pairs per wave, 16 lanes each
__global__ void k_dot_sig(const uint2* __restrict__ x2, const int* __restrict__ uidx,
                          const int* __restrict__ vidx, float* __restrict__ out,
                          int batch, int numUsers) {
    int lane = threadIdx.x & 63;
    int gl = lane & 15;
    int q = (int)(((blockIdx.x * blockDim.x + threadIdx.x) >> 6) * 4 + (lane >> 4));
    if (q >= batch) return;
    int u = uidx[q];
    int v = vidx[q] + numUsers;
    uint2 a = x2[(size_t)u * 16 + gl];
    uint2 c = x2[(size_t)v * 16 + gl];
    float p = bflo(a.x) * bflo(c.x) + bfhi(a.x) * bfhi(c.x)
            + bflo(a.y) * bflo(c.y) + bfhi(a.y) * bfhi(c.y);
#pragma unroll
    for (int off = 1; off < 16; off <<= 1) p += __shfl_xor(p, off, 64);
    if (gl == 0) out[q] = 1.f / (1.f + __expf(-p));
}

// ---------------- host launch ----------------

static inline int cdiv(long long a, long long b) { return (int)((a + b - 1) / b); }

extern "C" void kernel_launch(void* const* d_in, const int* in_sizes, int n_in,
                              void* d_out, int out_size, void* d_ws, size_t ws_size,
                              hipStream_t stream) {
    const int* edge_index = (const int*)d_in[0];
    const int* buidx      = (const int*)d_in[1];
    const int* biidx      = (const int*)d_in[2];
    const float* user_emb = (const float*)d_in[3];
    const float* item_emb = (const float*)d_in[4];
    const float* W1     = (const float*)d_in[5];
    const float* a_src1 = (const float*)d_in[6];
    const float* a_dst1 = (const float*)d_in[7];
    const float* b1     = (const float*)d_in[8];
    const float* W2     = (const float*)d_in[9];
    const float* a_src2 = (const float*)d_in[10];
    const float* a_dst2 = (const float*)d_in[11];
    const float* b2     = (const float*)d_in[12];
    float* out = (float*)d_out;

    const int E  = in_sizes[0] / 2;
    const int B  = in_sizes[1];
    const int NU = in_sizes[3] / 64;
    const int NI = in_sizes[4] / 64;
    const int N  = NU + NI;
    const int NB = cdiv(N, 1 << SHIFT);     // 586 for N=150000 (<= NBMAX)

    const int* src = edge_index;
    const int* dst = edge_index + E;

    // workspace carve (4-byte units)
    float* ws = (float*)d_ws;
    size_t off = 0;
    unsigned* x_buf  = (unsigned*)(ws + off); off += (size_t)N * 32;   // bf16 x (128B rows)
    unsigned* h_buf  = (unsigned*)(ws + off); off += (size_t)N * 16;   // fp8 h (64B rows)
    float*    as_b   = ws + off; off += (size_t)N * 4;
    float*    ad_b   = ws + off; off += (size_t)N * 4;
    unsigned* gcur_b = (unsigned*)(ws + off); off += NBMAX;
    unsigned* beg_b  = (unsigned*)(ws + off); off += (size_t)N;
    unsigned* end_b  = (unsigned*)(ws + off); off += (size_t)N;
    unsigned* pairs_b= (unsigned*)(ws + off); off += (size_t)NB * CAP;
    int*      srt_b  = (int*)(ws + off); off += (size_t)NB * CAP;
    unsigned short* wt1_b = (unsigned short*)(ws + off); off += 2048;
    unsigned short* wt2_b = (unsigned short*)(ws + off); off += 2048;

    const int BS = 256;

    // ---------- prep (folded) + LDS-staged bucket partition ----------
    hipMemsetAsync(gcur_b, 0, NBMAX * sizeof(unsigned), stream);
    k_partition<<<cdiv(E, TILE), 512, 0, stream>>>(src, dst, E, gcur_b, pairs_b, NB,
                                                   W1, W2, wt1_b, wt2_b);

    // ---------- bucket sort || layer-1 linear (merged, independent) ----------
    k_buck_lin<<<NB + cdiv(N, 64), 512, 0, stream>>>(
        pairs_b, gcur_b, beg_b, end_b, srt_b, N, NB,
        user_emb, item_emb, NU, wt1_b, a_src1, a_dst1,
        (unsigned char*)h_buf, as_b, ad_b);

    // ---------- gat layer 1 (H=4) ----------
    k_gat<4><<<cdiv((long long)N * 16, BS), BS, 0, stream>>>(
        srt_b, beg_b, end_b, h_buf, as_b, ad_b, b1, x_buf, N);

    // ---------- layer 2 : H=1, F=64 (bf16 x) ----------
    k_linear_mfma<1, 1><<<cdiv(N, 64), BS, 0, stream>>>(x_buf, x_buf, N, wt2_b,
                                                        a_src2, a_dst2,
                                                        (unsigned char*)h_buf, as_b, ad_b, N);
    k_gat<1><<<cdiv((long long)N * 16, BS), BS, 0, stream>>>(
        srt_b, beg_b, end_b, h_buf, as_b, ad_b, b2, x_buf, N);

    // ---------- final: sigmoid(dot) ----------
    k_dot_sig<<<cdiv((long long)B * 16, BS), BS, 0, stream>>>(
        (const uint2*)x_buf, buidx, biidx, out, B, NU);
}